// Round 2
// baseline (471.786 us; speedup 1.0000x reference)
//
#include <hip/hip_runtime.h>
#include <hip/hip_bf16.h>

namespace {

constexpr int S_LEN = 2048;
constexpr int DH    = 128;
constexpr int QT    = 128;            // q rows per block (4 waves x 32)
constexpr int KVB   = 64;             // kv rows per tile
constexpr int NQT   = S_LEN / QT;     // 16

typedef __attribute__((ext_vector_type(8)))  short  short8;
typedef __attribute__((ext_vector_type(8)))  __bf16 bf16x8;
typedef __attribute__((ext_vector_type(4)))  float  f32x4;
typedef __attribute__((ext_vector_type(16))) float  f32x16;

__device__ __forceinline__ unsigned pk2(float a, float b) {
    unsigned short lo = __builtin_bit_cast(unsigned short, __float2bfloat16(a));
    unsigned short hh = __builtin_bit_cast(unsigned short, __float2bfloat16(b));
    return (unsigned)lo | ((unsigned)hh << 16);
}
__device__ __forceinline__ f32x16 mfma32(short8 a, short8 b, f32x16 c) {
    return __builtin_amdgcn_mfma_f32_32x32x16_bf16(
        __builtin_bit_cast(bf16x8, a), __builtin_bit_cast(bf16x8, b), c, 0, 0, 0);
}
__device__ __forceinline__ f32x16 zero16() {
    f32x16 z;
    #pragma unroll
    for (int i = 0; i < 16; ++i) z[i] = 0.f;
    return z;
}

__global__ void __launch_bounds__(256, 3)
attn_fwd(const float* __restrict__ Qp, const float* __restrict__ Kp,
         const float* __restrict__ Vp, float* __restrict__ Op)
{
    __shared__ __align__(16) short ksm[KVB * DH];   // K tile [64][128] bf16, XOR-swizzled
    __shared__ __align__(16) short vtm[DH * KVB];   // V^T tile [128][64] bf16, XOR-swizzled

    const int x   = blockIdx.x;
    const int qt  = (x & 1) ? (x >> 1) : (NQT - 1 - (x >> 1));  // heavy/light interleave
    const int bh  = blockIdx.y;
    const int tid = threadIdx.x;
    const int w   = tid >> 6;
    const int l   = tid & 63;
    const int r31 = l & 31;
    const int hi  = l >> 5;

    const size_t base = (size_t)bh * (S_LEN * DH);
    const int qw = qt * QT + 32 * w;       // wave's first q row
    const int qg = qw + r31;               // lane's q row

    const float QS = 0.08838834764831845f * 1.4426950408889634f; // 1/sqrt(128)*log2(e)

    // ---- Q fragments (B-operand: col=q=r31, kk=8*hi+j, one frag per 16-d slice) ----
    short8 qb[8];
    {
        const float* qrow = Qp + base + (size_t)qg * DH + 8 * hi;
        #pragma unroll
        for (int t = 0; t < 8; ++t) {
            f32x4 f0 = *reinterpret_cast<const f32x4*>(qrow + 16 * t);
            f32x4 f1 = *reinterpret_cast<const f32x4*>(qrow + 16 * t + 4);
            uint4 u;
            u.x = pk2(f0[0] * QS, f0[1] * QS);
            u.y = pk2(f0[2] * QS, f0[3] * QS);
            u.z = pk2(f1[0] * QS, f1[1] * QS);
            u.w = pk2(f1[2] * QS, f1[3] * QS);
            qb[t] = __builtin_bit_cast(short8, u);
        }
    }

    f32x16 acc_o[4];
    #pragma unroll
    for (int i = 0; i < 4; ++i) acc_o[i] = zero16();
    float m_run = -1e30f, l_run = 0.f;

    const int vd  = tid >> 1;          // V gather: d row 0..127
    const int vkh = (tid & 1) * 32;    // V gather: k half

    const int nkt = (qt + 1) * (QT / KVB);   // tiles up to and incl. diagonal
    for (int kt = 0; kt < nkt; ++kt) {
        const int k0 = kt * KVB;
        __syncthreads();
        // ---- stage K: [64][128] fp32 -> bf16 LDS, swizzle e ^ ((row&15)<<3) ----
        #pragma unroll
        for (int c = 0; c < 8; ++c) {
            const int row = (tid >> 5) + 8 * c;
            const int dq  = (tid & 31) * 4;
            f32x4 f = *reinterpret_cast<const f32x4*>(Kp + base + (size_t)(k0 + row) * DH + dq);
            uint2 u;
            u.x = pk2(f[0], f[1]);
            u.y = pk2(f[2], f[3]);
            const int si = (row * DH + dq) ^ ((row & 15) << 3);
            *reinterpret_cast<uint2*>(&ksm[si]) = u;
        }
        // ---- stage V^T: gather columns, pack 8-k runs, swizzle e ^ ((d&7)<<3) ----
        {
            float vg[32];
            #pragma unroll
            for (int j = 0; j < 32; ++j)
                vg[j] = Vp[base + (size_t)(k0 + vkh + j) * DH + vd];
            #pragma unroll
            for (int t2 = 0; t2 < 4; ++t2) {
                uint4 u;
                u.x = pk2(vg[8 * t2 + 0], vg[8 * t2 + 1]);
                u.y = pk2(vg[8 * t2 + 2], vg[8 * t2 + 3]);
                u.z = pk2(vg[8 * t2 + 4], vg[8 * t2 + 5]);
                u.w = pk2(vg[8 * t2 + 6], vg[8 * t2 + 7]);
                const int si = (vd * KVB + vkh + 8 * t2) ^ ((vd & 7) << 3);
                *reinterpret_cast<uint4*>(&vtm[si]) = u;
            }
        }
        __syncthreads();

        if (k0 <= qw + 31) {
            // ---- QK^T (swapped): S^T[k][q], lane holds q=r31, k=crow(reg,hi)+32a ----
            f32x16 s0 = zero16(), s1 = zero16();
            __builtin_amdgcn_s_setprio(1);
            #pragma unroll
            for (int t = 0; t < 8; ++t) {
                const int e0 = (r31 * DH + 16 * t + 8 * hi) ^ ((r31 & 15) << 3);
                short8 ka = *reinterpret_cast<const short8*>(&ksm[e0]);
                s0 = mfma32(ka, qb[t], s0);
                const int e1 = ((r31 + 32) * DH + 16 * t + 8 * hi) ^ ((r31 & 15) << 3);
                short8 kb = *reinterpret_cast<const short8*>(&ksm[e1]);
                s1 = mfma32(kb, qb[t], s1);
            }
            __builtin_amdgcn_s_setprio(0);

            // ---- causal mask (diagonal-crossing tiles only) ----
            if (k0 + KVB - 1 > qw) {
                #pragma unroll
                for (int rg = 0; rg < 16; ++rg) {
                    const int kl = (rg & 3) + 8 * (rg >> 2) + 4 * hi;
                    if (k0 + kl > qg)      s0[rg] = -3.0e38f;
                    if (k0 + 32 + kl > qg) s1[rg] = -3.0e38f;
                }
            }

            // ---- online softmax, fully in-register (exp2 domain) ----
            float tm[16];
            #pragma unroll
            for (int i = 0; i < 16; ++i) tm[i] = fmaxf(s0[i], s1[i]);
            #pragma unroll
            for (int st = 8; st > 0; st >>= 1)
                #pragma unroll
                for (int i = 0; i < st; ++i) tm[i] = fmaxf(tm[i], tm[i + st]);
            const float mt = fmaxf(tm[0], __shfl_xor(tm[0], 32));
            const float mn = fmaxf(m_run, mt);
            const float al = exp2f(m_run - mn);
            m_run = mn;
            #pragma unroll
            for (int i = 0; i < 16; ++i) { s0[i] = exp2f(s0[i] - mn); s1[i] = exp2f(s1[i] - mn); }
            float ts[16];
            #pragma unroll
            for (int i = 0; i < 16; ++i) ts[i] = s0[i] + s1[i];
            #pragma unroll
            for (int st = 8; st > 0; st >>= 1)
                #pragma unroll
                for (int i = 0; i < st; ++i) ts[i] += ts[i + st];
            const float sm = ts[0] + __shfl_xor(ts[0], 32);
            l_run = l_run * al + sm;
            #pragma unroll
            for (int d0 = 0; d0 < 4; ++d0)
                #pragma unroll
                for (int i = 0; i < 16; ++i) acc_o[d0][i] *= al;

            // ---- P -> bf16 B-fragments via cvt_pk + permlane32_swap ----
            short8 pbs[4];
            #pragma unroll
            for (int a = 0; a < 2; ++a) {
                f32x16 s = a ? s1 : s0;
                #pragma unroll
                for (int h = 0; h < 2; ++h) {
                    unsigned a1 = pk2(s[8 * h + 0], s[8 * h + 1]);
                    unsigned a2 = pk2(s[8 * h + 2], s[8 * h + 3]);
                    unsigned b1 = pk2(s[8 * h + 4], s[8 * h + 5]);
                    unsigned b2 = pk2(s[8 * h + 6], s[8 * h + 7]);
                    asm volatile("v_permlane32_swap_b32 %0, %1" : "+v"(a1), "+v"(b1));
                    asm volatile("v_permlane32_swap_b32 %0, %1" : "+v"(a2), "+v"(b2));
                    uint4 u; u.x = a1; u.y = a2; u.z = b1; u.w = b2;
                    pbs[2 * a + h] = __builtin_bit_cast(short8, u);
                }
            }

            // ---- PV: O^T = V^T x P^T ; acc_o[d0][reg] = O[q=r31][d=crow+32*d0] ----
            __builtin_amdgcn_s_setprio(1);
            #pragma unroll
            for (int d0 = 0; d0 < 4; ++d0) {
                const int vr = 32 * d0 + r31;
                #pragma unroll
                for (int ks = 0; ks < 4; ++ks) {
                    const int e = (vr * KVB + 16 * ks + 8 * hi) ^ ((vr & 7) << 3);
                    short8 vf = *reinterpret_cast<const short8*>(&vtm[e]);
                    acc_o[d0] = mfma32(vf, pbs[ks], acc_o[d0]);
                }
            }
            __builtin_amdgcn_s_setprio(0);
        }
    }

    // ---- epilogue: normalize, store fp32 ----
    const float rl = 1.0f / l_run;
    float* orow = Op + base + (size_t)qg * DH;
    #pragma unroll
    for (int d0 = 0; d0 < 4; ++d0) {
        #pragma unroll
        for (int rg = 0; rg < 4; ++rg) {
            f32x4 v;
            v[0] = acc_o[d0][4 * rg + 0] * rl;
            v[1] = acc_o[d0][4 * rg + 1] * rl;
            v[2] = acc_o[d0][4 * rg + 2] * rl;
            v[3] = acc_o[d0][4 * rg + 3] * rl;
            *reinterpret_cast<f32x4*>(orow + 32 * d0 + 8 * rg + 4 * hi) = v;
        }
    }
}

} // namespace

extern "C" void kernel_launch(void* const* d_in, const int* in_sizes, int n_in,
                              void* d_out, int out_size, void* d_ws, size_t ws_size,
                              hipStream_t stream)
{
    const float* Q = (const float*)d_in[0];
    const float* K = (const float*)d_in[1];
    const float* V = (const float*)d_in[2];
    float* O = (float*)d_out;
    dim3 grid(NQT, 32);
    dim3 block(256);
    hipLaunchKernelGGL(attn_fwd, grid, block, 0, stream, Q, K, V, O);
}

// Round 3
// 430.241 us; speedup vs baseline: 1.0966x; 1.0966x over previous
//
#include <hip/hip_runtime.h>
#include <hip/hip_bf16.h>

namespace {

constexpr int S_LEN = 2048;
constexpr int DH    = 128;
constexpr int QT    = 128;            // q rows per block (4 waves x 32)
constexpr int KVB   = 64;             // kv rows per tile
constexpr int NQT   = S_LEN / QT;     // 16

typedef __attribute__((ext_vector_type(8)))  short  short8;
typedef __attribute__((ext_vector_type(8)))  __bf16 bf16x8;
typedef __attribute__((ext_vector_type(4)))  float  f32x4;
typedef __attribute__((ext_vector_type(16))) float  f32x16;

__device__ __forceinline__ short f2bf(float x) {
    return __builtin_bit_cast(short, __float2bfloat16(x));
}
__device__ __forceinline__ unsigned pk2(float a, float b) {
    unsigned short lo = __builtin_bit_cast(unsigned short, __float2bfloat16(a));
    unsigned short hh = __builtin_bit_cast(unsigned short, __float2bfloat16(b));
    return (unsigned)lo | ((unsigned)hh << 16);
}
__device__ __forceinline__ f32x16 mfma32(short8 a, short8 b, f32x16 c) {
    return __builtin_amdgcn_mfma_f32_32x32x16_bf16(
        __builtin_bit_cast(bf16x8, a), __builtin_bit_cast(bf16x8, b), c, 0, 0, 0);
}
__device__ __forceinline__ f32x16 zero16() {
    f32x16 z;
    #pragma unroll
    for (int i = 0; i < 16; ++i) z[i] = 0.f;
    return z;
}

__global__ void __launch_bounds__(256, 2)
attn_fwd(const float* __restrict__ Qp, const float* __restrict__ Kp,
         const float* __restrict__ Vp, float* __restrict__ Op)
{
    // double-buffered: K row-major [64][128], V^T [128][64], both bf16 + XOR swizzle
    __shared__ __align__(16) short ksm[2][KVB * DH];
    __shared__ __align__(16) short vtm[2][DH * KVB];

    const int x   = blockIdx.x;
    // XCD-balanced map: blocks x and x+8 land on the same XCD (round-robin %8)
    // and their tile counts sum to a constant: qt(x)+qt(x+8) = 15.
    const int qt  = (x < 8) ? (NQT - 1 - x) : (x - 8);
    const int bh  = blockIdx.y;
    const int tid = threadIdx.x;
    const int w   = tid >> 6;
    const int l   = tid & 63;
    const int r31 = l & 31;
    const int hi  = l >> 5;

    const size_t base = (size_t)bh * (S_LEN * DH);
    const int qw = qt * QT + 32 * w;       // wave's first q row
    const int qg = qw + r31;               // lane's q row

    const float QS = 0.08838834764831845f * 1.4426950408889634f; // 1/sqrt(128)*log2(e)

    // staging index: fully-coalesced flat mapping (elem = 4*tid + 1024*i)
    const int srow = tid >> 5;            // 0..7 (+8*i)
    const int scol = (tid & 31) * 4;      // 0..124

    const float* Kb = Kp + base;
    const float* Vb = Vp + base;

    // ---- Q fragments (B-operand: col=q=r31, kk=8*hi+j per 16-d slice) ----
    short8 qb[8];
    {
        const float* qrow = Qp + base + (size_t)qg * DH + 8 * hi;
        #pragma unroll
        for (int t = 0; t < 8; ++t) {
            f32x4 f0 = *reinterpret_cast<const f32x4*>(qrow + 16 * t);
            f32x4 f1 = *reinterpret_cast<const f32x4*>(qrow + 16 * t + 4);
            uint4 u;
            u.x = pk2(f0[0] * QS, f0[1] * QS);
            u.y = pk2(f0[2] * QS, f0[3] * QS);
            u.z = pk2(f1[0] * QS, f1[1] * QS);
            u.w = pk2(f1[2] * QS, f1[3] * QS);
            qb[t] = __builtin_bit_cast(short8, u);
        }
    }

    f32x4 kpf[8], vpf[8];   // prefetch registers (issue-early / write-late)
    auto issue_loads = [&](int k0) {
        const float* kr = Kb + (size_t)(k0 + srow) * DH + scol;
        const float* vr = Vb + (size_t)(k0 + srow) * DH + scol;
        #pragma unroll
        for (int i = 0; i < 8; ++i) {
            kpf[i] = *reinterpret_cast<const f32x4*>(kr + (size_t)(8 * i) * DH);
            vpf[i] = *reinterpret_cast<const f32x4*>(vr + (size_t)(8 * i) * DH);
        }
    };
    auto write_tiles = [&](int b) {
        short* ks = ksm[b];
        short* vt = vtm[b];
        #pragma unroll
        for (int i = 0; i < 8; ++i) {
            const int row = srow + 8 * i;
            uint2 u;
            u.x = pk2(kpf[i][0], kpf[i][1]);
            u.y = pk2(kpf[i][2], kpf[i][3]);
            *reinterpret_cast<uint2*>(&ks[(row * DH + scol) ^ ((row & 15) << 3)]) = u;
            #pragma unroll
            for (int j = 0; j < 4; ++j) {
                const int d = scol + j;
                vt[(d * KVB + row) ^ ((d & 7) << 3)] = f2bf(vpf[i][j]);
            }
        }
    };

    f32x16 acc_o[4];
    #pragma unroll
    for (int i = 0; i < 4; ++i) acc_o[i] = zero16();
    float m_run = -1e30f, l_run = 0.f;

    // ---- prologue: stage tile 0 ----
    issue_loads(0);
    write_tiles(0);
    __syncthreads();
    int cur = 0;

    const int nkt = (qt + 1) * (QT / KVB);
    for (int kt = 0; kt < nkt; ++kt) {
        const int k0   = kt * KVB;
        const bool more = (kt + 1 < nkt);
        if (more) issue_loads(k0 + KVB);       // overlap HBM latency with compute

        if (k0 <= qw) {
            const bool useS1 = (k0 < qw);      // s1 half (k rows +32..63) has any valid k
            const short* ks = ksm[cur];
            const short* vt = vtm[cur];

            // ---- QK^T (swapped): lane holds q=r31, k = crow(rg,hi) (+32 for s1) ----
            f32x16 s0 = zero16(), s1 = zero16();
            __builtin_amdgcn_s_setprio(1);
            if (useS1) {
                #pragma unroll
                for (int t = 0; t < 8; ++t) {
                    const int c = 16 * t + 8 * hi;
                    short8 ka = *reinterpret_cast<const short8*>(
                        &ks[(r31 * DH + c) ^ ((r31 & 15) << 3)]);
                    short8 kb2 = *reinterpret_cast<const short8*>(
                        &ks[((r31 + 32) * DH + c) ^ (((r31 + 32) & 15) << 3)]);
                    s0 = mfma32(ka,  qb[t], s0);
                    s1 = mfma32(kb2, qb[t], s1);
                }
            } else {
                #pragma unroll
                for (int t = 0; t < 8; ++t) {
                    const int c = 16 * t + 8 * hi;
                    short8 ka = *reinterpret_cast<const short8*>(
                        &ks[(r31 * DH + c) ^ ((r31 & 15) << 3)]);
                    s0 = mfma32(ka, qb[t], s0);
                }
            }
            __builtin_amdgcn_s_setprio(0);

            // ---- causal mask (diagonal-adjacent tiles only) ----
            if (k0 == qw) {
                #pragma unroll
                for (int rg = 0; rg < 16; ++rg) {
                    const int kl = (rg & 3) + 8 * (rg >> 2) + 4 * hi;
                    if (k0 + kl > qg) s0[rg] = -3.0e38f;
                }
            }
            if (useS1 && (k0 + 32 == qw)) {
                #pragma unroll
                for (int rg = 0; rg < 16; ++rg) {
                    const int kl = (rg & 3) + 8 * (rg >> 2) + 4 * hi;
                    if (k0 + 32 + kl > qg) s1[rg] = -3.0e38f;
                }
            }

            // ---- online softmax, in-register, exp2 domain, defer-max (T13) ----
            float tm[16];
            #pragma unroll
            for (int i = 0; i < 16; ++i) tm[i] = useS1 ? fmaxf(s0[i], s1[i]) : s0[i];
            #pragma unroll
            for (int st = 8; st > 0; st >>= 1)
                #pragma unroll
                for (int i = 0; i < st; ++i) tm[i] = fmaxf(tm[i], tm[i + st]);
            const float mt = fmaxf(tm[0], __shfl_xor(tm[0], 32));

            float mn = m_run;
            if (!__all(mt <= m_run + 8.0f)) {
                mn = fmaxf(m_run, mt);
                const float al = exp2f(m_run - mn);
                m_run = mn;
                l_run *= al;
                #pragma unroll
                for (int d0 = 0; d0 < 4; ++d0)
                    #pragma unroll
                    for (int i = 0; i < 16; ++i) acc_o[d0][i] *= al;
            }

            #pragma unroll
            for (int i = 0; i < 16; ++i) s0[i] = exp2f(s0[i] - mn);
            if (useS1) {
                #pragma unroll
                for (int i = 0; i < 16; ++i) s1[i] = exp2f(s1[i] - mn);
            }
            float ts[16];
            #pragma unroll
            for (int i = 0; i < 16; ++i) ts[i] = useS1 ? (s0[i] + s1[i]) : s0[i];
            #pragma unroll
            for (int st = 8; st > 0; st >>= 1)
                #pragma unroll
                for (int i = 0; i < st; ++i) ts[i] += ts[i + st];
            l_run += ts[0] + __shfl_xor(ts[0], 32);

            // ---- P -> bf16 fragments via cvt_pk + permlane32_swap (T12) ----
            short8 pbs[4];
            auto mkpb = [&](const f32x16& s, short8* out) {
                #pragma unroll
                for (int h = 0; h < 2; ++h) {
                    unsigned a1 = pk2(s[8 * h + 0], s[8 * h + 1]);
                    unsigned a2 = pk2(s[8 * h + 2], s[8 * h + 3]);
                    unsigned b1 = pk2(s[8 * h + 4], s[8 * h + 5]);
                    unsigned b2 = pk2(s[8 * h + 6], s[8 * h + 7]);
                    asm volatile("v_permlane32_swap_b32 %0, %1" : "+v"(a1), "+v"(b1));
                    asm volatile("v_permlane32_swap_b32 %0, %1" : "+v"(a2), "+v"(b2));
                    uint4 u; u.x = a1; u.y = a2; u.z = b1; u.w = b2;
                    out[h] = __builtin_bit_cast(short8, u);
                }
            };
            mkpb(s0, &pbs[0]);
            if (useS1) mkpb(s1, &pbs[2]);

            // ---- PV: O^T = V^T x P^T ; acc_o[d0][rg] = O[q=r31][d=crow+32*d0] ----
            __builtin_amdgcn_s_setprio(1);
            #pragma unroll
            for (int d0 = 0; d0 < 4; ++d0) {
                const int vr = 32 * d0 + r31;
                #pragma unroll
                for (int ksl = 0; ksl < 2; ++ksl) {
                    const int e = (vr * KVB + 16 * ksl + 8 * hi) ^ ((vr & 7) << 3);
                    short8 vf = *reinterpret_cast<const short8*>(&vt[e]);
                    acc_o[d0] = mfma32(vf, pbs[ksl], acc_o[d0]);
                }
            }
            if (useS1) {
                #pragma unroll
                for (int d0 = 0; d0 < 4; ++d0) {
                    const int vr = 32 * d0 + r31;
                    #pragma unroll
                    for (int ksl = 2; ksl < 4; ++ksl) {
                        const int e = (vr * KVB + 16 * ksl + 8 * hi) ^ ((vr & 7) << 3);
                        short8 vf = *reinterpret_cast<const short8*>(&vt[e]);
                        acc_o[d0] = mfma32(vf, pbs[ksl], acc_o[d0]);
                    }
                }
            }
            __builtin_amdgcn_s_setprio(0);
        }

        if (more) {
            write_tiles(cur ^ 1);   // vmcnt wait lands here, after compute
            __syncthreads();        // single barrier per tile
            cur ^= 1;
        }
    }

    // ---- epilogue: normalize, store fp32 ----
    const float rl = 1.0f / l_run;
    float* orow = Op + base + (size_t)qg * DH;
    #pragma unroll
    for (int d0 = 0; d0 < 4; ++d0) {
        #pragma unroll
        for (int rg = 0; rg < 4; ++rg) {
            f32x4 v;
            v[0] = acc_o[d0][4 * rg + 0] * rl;
            v[1] = acc_o[d0][4 * rg + 1] * rl;
            v[2] = acc_o[d0][4 * rg + 2] * rl;
            v[3] = acc_o[d0][4 * rg + 3] * rl;
            *reinterpret_cast<f32x4*>(orow + 32 * d0 + 8 * rg + 4 * hi) = v;
        }
    }
}

} // namespace

extern "C" void kernel_launch(void* const* d_in, const int* in_sizes, int n_in,
                              void* d_out, int out_size, void* d_ws, size_t ws_size,
                              hipStream_t stream)
{
    const float* Q = (const float*)d_in[0];
    const float* K = (const float*)d_in[1];
    const float* V = (const float*)d_in[2];
    float* O = (float*)d_out;
    dim3 grid(NQT, 32);
    dim3 block(256);
    hipLaunchKernelGGL(attn_fwd, grid, block, 0, stream, Q, K, V, O);
}

// Round 4
// 295.622 us; speedup vs baseline: 1.5959x; 1.4554x over previous
//
#include <hip/hip_runtime.h>
#include <hip/hip_bf16.h>

namespace {

constexpr int S_LEN = 2048;
constexpr int DH    = 128;
constexpr int KVB   = 64;             // kv rows per tile
constexpr int QT    = 256;            // q rows per block (8 waves x 32)
constexpr int NQT   = S_LEN / QT;     // 8 strips

typedef __attribute__((ext_vector_type(2)))  float  f32x2;
typedef __attribute__((ext_vector_type(4)))  float  f32x4;
typedef __attribute__((ext_vector_type(16))) float  f32x16;
typedef __attribute__((ext_vector_type(8)))  short  short8;
typedef __attribute__((ext_vector_type(8)))  __bf16 bf16x8;

__device__ __forceinline__ unsigned pk2(float a, float b) {
    unsigned short lo = __builtin_bit_cast(unsigned short, __float2bfloat16(a));
    unsigned short hh = __builtin_bit_cast(unsigned short, __float2bfloat16(b));
    return (unsigned)lo | ((unsigned)hh << 16);
}
__device__ __forceinline__ f32x16 mfma32(short8 a, short8 b, f32x16 c) {
    return __builtin_amdgcn_mfma_f32_32x32x16_bf16(
        __builtin_bit_cast(bf16x8, a), __builtin_bit_cast(bf16x8, b), c, 0, 0, 0);
}
__device__ __forceinline__ f32x16 zero16() {
    f32x16 z;
    #pragma unroll
    for (int i = 0; i < 16; ++i) z[i] = 0.f;
    return z;
}
__device__ __forceinline__ short8 mk8(unsigned a, unsigned b, unsigned c, unsigned d) {
    uint4 u; u.x = a; u.y = b; u.z = c; u.w = d;
    return __builtin_bit_cast(short8, u);
}

__global__ void __launch_bounds__(512, 2)
attn_fwd(const float* __restrict__ Qp, const float* __restrict__ Kp,
         const float* __restrict__ Vp, float* __restrict__ Op)
{
    // double-buffered bf16 tiles; 4-short-granule XOR swizzles, b64 reads
    __shared__ __align__(16) short ksm[2][KVB * DH];   // K  [64][128]
    __shared__ __align__(16) short vtm[2][DH * KVB];   // V^T[128][64]

    const int c   = blockIdx.x;        // 0..255  (1 block per CU)
    const int bh  = c & 31;
    const int p   = c >> 5;            // 0..7
    const int tid = threadIdx.x;
    const int l   = tid & 63;
    const int w   = tid >> 6;          // wave 0..7
    const int r31 = l & 31;
    const int hi  = l >> 5;

    const size_t base = (size_t)bh * (S_LEN * DH);
    const float* Kb = Kp + base;
    const float* Vb = Vp + base;

    const float QS = 0.08838834764831845f * 1.4426950408889634f; // 1/sqrt(128)*log2(e)

    // staging maps (coalesced: full 512B rows per wave)
    const int krow = tid >> 5;          // 0..15 (+16 per i)
    const int kcol = (tid & 31) * 4;    // 0..124
    const int vrp  = tid >> 6;          // 0..7 (+8 per i) -> k pair 2*rp
    const int vcol = (tid & 63) * 2;    // d pair 0..126

    f32x4 kpf[4];
    f32x2 vpf[4][2];

    auto issueT = [&](int k0) {
        #pragma unroll
        for (int i = 0; i < 4; ++i)
            kpf[i] = *reinterpret_cast<const f32x4*>(
                Kb + (size_t)(k0 + krow + 16 * i) * DH + kcol);
        #pragma unroll
        for (int i = 0; i < 4; ++i) {
            const int kk = k0 + 2 * (vrp + 8 * i);
            vpf[i][0] = *reinterpret_cast<const f32x2*>(Vb + (size_t)kk * DH + vcol);
            vpf[i][1] = *reinterpret_cast<const f32x2*>(Vb + (size_t)(kk + 1) * DH + vcol);
        }
    };
    auto writeT = [&](int b) {
        short* ks = ksm[b];
        short* vt = vtm[b];
        #pragma unroll
        for (int i = 0; i < 4; ++i) {
            const int row = krow + 16 * i;
            uint2 u;
            u.x = pk2(kpf[i][0], kpf[i][1]);
            u.y = pk2(kpf[i][2], kpf[i][3]);
            *reinterpret_cast<uint2*>(&ks[(row * DH + kcol) ^ ((row & 15) << 2)]) = u;
        }
        #pragma unroll
        for (int i = 0; i < 4; ++i) {
            const int k2 = 2 * (vrp + 8 * i);
            #pragma unroll
            for (int e = 0; e < 2; ++e) {
                const int d = vcol + e;
                const unsigned u = pk2(vpf[i][0][e], vpf[i][1][e]);
                *reinterpret_cast<unsigned*>(
                    &vt[(d * KVB + k2) ^ (((d >> 1) & 15) << 2)]) = u;
            }
        }
    };
    auto ldK = [&](const short* ks, int row, int col) -> short8 {
        const int sw = (row & 15) << 2;
        const uint2 a = *reinterpret_cast<const uint2*>(&ks[(row * DH + col) ^ sw]);
        const uint2 b = *reinterpret_cast<const uint2*>(&ks[(row * DH + col + 4) ^ sw]);
        return mk8(a.x, a.y, b.x, b.y);
    };
    auto ldV = [&](const short* vt, int vr, int col) -> short8 {
        const int sw = ((vr >> 1) & 15) << 2;
        const uint2 a = *reinterpret_cast<const uint2*>(&vt[(vr * KVB + col) ^ sw]);
        const uint2 b = *reinterpret_cast<const uint2*>(&vt[(vr * KVB + col + 4) ^ sw]);
        return mk8(a.x, a.y, b.x, b.y);
    };

    // two strips per block: qt = p and 7-p -> constant 36 tiles per block
    #pragma unroll 1
    for (int sidx = 0; sidx < 2; ++sidx) {
        const int qt  = sidx ? (NQT - 1 - p) : p;
        const int qw  = qt * QT + 32 * w;     // wave's first q row
        const int qg  = qw + r31;             // lane's q row
        const int nkt = (qt + 1) * (QT / KVB);

        // Q fragments (B-operand: col=q=r31, k-elem = 8hi+j per 16-d slice)
        short8 qb[8];
        {
            const float* qrow = Qp + base + (size_t)qg * DH + 8 * hi;
            #pragma unroll
            for (int t = 0; t < 8; ++t) {
                f32x4 f0 = *reinterpret_cast<const f32x4*>(qrow + 16 * t);
                f32x4 f1 = *reinterpret_cast<const f32x4*>(qrow + 16 * t + 4);
                qb[t] = mk8(pk2(f0[0] * QS, f0[1] * QS), pk2(f0[2] * QS, f0[3] * QS),
                            pk2(f1[0] * QS, f1[1] * QS), pk2(f1[2] * QS, f1[3] * QS));
            }
        }

        f32x16 acc_o[4];
        #pragma unroll
        for (int i = 0; i < 4; ++i) acc_o[i] = zero16();
        float m_run = -1e30f, l_run = 0.f;

        __syncthreads();                 // previous strip done with LDS
        issueT(0);
        writeT(0);
        __syncthreads();
        if (nkt > 1) issueT(KVB);
        __builtin_amdgcn_sched_barrier(0);   // pin prefetch issue before compute
        int cur = 0;

        for (int kt = 0; kt < nkt; ++kt) {
            const int k0 = kt * KVB;
            const short* ks = ksm[cur];
            const short* vt = vtm[cur];

            if (k0 <= qw) {                      // wave has valid k in this tile
                const bool useS1 = (k0 < qw);    // upper half (k0+32..63) valid

                // ---- QK^T (swapped): lane q=r31, k=crow(rg,hi) (+32 in s1) ----
                f32x16 s0 = zero16(), s1 = zero16();
                __builtin_amdgcn_s_setprio(1);
                #pragma unroll
                for (int t = 0; t < 8; ++t)
                    s0 = mfma32(ldK(ks, r31, 16 * t + 8 * hi), qb[t], s0);
                if (useS1) {
                    #pragma unroll
                    for (int t = 0; t < 8; ++t)
                        s1 = mfma32(ldK(ks, r31 + 32, 16 * t + 8 * hi), qb[t], s1);
                }
                __builtin_amdgcn_s_setprio(0);

                // ---- causal mask (diagonal tiles only) ----
                if (k0 == qw) {
                    #pragma unroll
                    for (int rg = 0; rg < 16; ++rg) {
                        const int kl = (rg & 3) + 8 * (rg >> 2) + 4 * hi;
                        if (k0 + kl > qg) s0[rg] = -3.0e38f;
                    }
                }
                if (useS1 && (k0 + 32 == qw)) {
                    #pragma unroll
                    for (int rg = 0; rg < 16; ++rg) {
                        const int kl = (rg & 3) + 8 * (rg >> 2) + 4 * hi;
                        if (k0 + 32 + kl > qg) s1[rg] = -3.0e38f;
                    }
                }

                // ---- online softmax (in-register, exp2 domain, defer-max) ----
                float tm[16];
                #pragma unroll
                for (int i = 0; i < 16; ++i) tm[i] = useS1 ? fmaxf(s0[i], s1[i]) : s0[i];
                #pragma unroll
                for (int st = 8; st > 0; st >>= 1)
                    #pragma unroll
                    for (int i = 0; i < st; ++i) tm[i] = fmaxf(tm[i], tm[i + st]);
                const float mt = fmaxf(tm[0], __shfl_xor(tm[0], 32));

                float mn = m_run;
                if (!__all(mt <= m_run + 8.0f)) {
                    mn = fmaxf(m_run, mt);
                    const float al = exp2f(m_run - mn);
                    m_run = mn;
                    l_run *= al;
                    #pragma unroll
                    for (int d0 = 0; d0 < 4; ++d0)
                        #pragma unroll
                        for (int i = 0; i < 16; ++i) acc_o[d0][i] *= al;
                }

                #pragma unroll
                for (int i = 0; i < 16; ++i) s0[i] = exp2f(s0[i] - mn);
                if (useS1) {
                    #pragma unroll
                    for (int i = 0; i < 16; ++i) s1[i] = exp2f(s1[i] - mn);
                }
                float ts[16];
                #pragma unroll
                for (int i = 0; i < 16; ++i) ts[i] = useS1 ? (s0[i] + s1[i]) : s0[i];
                #pragma unroll
                for (int st = 8; st > 0; st >>= 1)
                    #pragma unroll
                    for (int i = 0; i < st; ++i) ts[i] += ts[i + st];
                l_run += ts[0] + __shfl_xor(ts[0], 32);

                // ---- P -> bf16 B-fragments (cvt_pk + permlane32_swap) ----
                short8 pbs[4];
                auto mkpb = [&](const f32x16& s, short8* out) {
                    #pragma unroll
                    for (int h = 0; h < 2; ++h) {
                        unsigned a1 = pk2(s[8 * h + 0], s[8 * h + 1]);
                        unsigned a2 = pk2(s[8 * h + 2], s[8 * h + 3]);
                        unsigned b1 = pk2(s[8 * h + 4], s[8 * h + 5]);
                        unsigned b2 = pk2(s[8 * h + 6], s[8 * h + 7]);
                        asm volatile("v_permlane32_swap_b32 %0, %1" : "+v"(a1), "+v"(b1));
                        asm volatile("v_permlane32_swap_b32 %0, %1" : "+v"(a2), "+v"(b2));
                        uint4 u; u.x = a1; u.y = a2; u.z = b1; u.w = b2;
                        out[h] = __builtin_bit_cast(short8, u);
                    }
                };
                mkpb(s0, &pbs[0]);
                if (useS1) mkpb(s1, &pbs[2]);

                // ---- PV: O^T = V^T x P^T ----
                __builtin_amdgcn_s_setprio(1);
                #pragma unroll
                for (int d0 = 0; d0 < 4; ++d0) {
                    const int vr = 32 * d0 + r31;
                    acc_o[d0] = mfma32(ldV(vt, vr, 8 * hi), pbs[0], acc_o[d0]);
                    acc_o[d0] = mfma32(ldV(vt, vr, 16 + 8 * hi), pbs[1], acc_o[d0]);
                }
                if (useS1) {
                    #pragma unroll
                    for (int d0 = 0; d0 < 4; ++d0) {
                        const int vr = 32 * d0 + r31;
                        acc_o[d0] = mfma32(ldV(vt, vr, 32 + 8 * hi), pbs[2], acc_o[d0]);
                        acc_o[d0] = mfma32(ldV(vt, vr, 48 + 8 * hi), pbs[3], acc_o[d0]);
                    }
                }
                __builtin_amdgcn_s_setprio(0);
            }

            if (kt + 1 < nkt) {
                writeT(cur ^ 1);             // vmcnt wait lands here
                __syncthreads();             // one barrier per tile
                cur ^= 1;
                if (kt + 2 < nkt) issueT((kt + 2) * KVB);
                __builtin_amdgcn_sched_barrier(0);  // keep next prefetch hoisted
            }
        }

        // ---- epilogue: normalize, store fp32 ----
        const float rl = 1.0f / l_run;
        float* orow = Op + base + (size_t)qg * DH;
        #pragma unroll
        for (int d0 = 0; d0 < 4; ++d0) {
            #pragma unroll
            for (int rg = 0; rg < 4; ++rg) {
                f32x4 v;
                v[0] = acc_o[d0][4 * rg + 0] * rl;
                v[1] = acc_o[d0][4 * rg + 1] * rl;
                v[2] = acc_o[d0][4 * rg + 2] * rl;
                v[3] = acc_o[d0][4 * rg + 3] * rl;
                *reinterpret_cast<f32x4*>(orow + 32 * d0 + 8 * rg + 4 * hi) = v;
            }
        }
    }
}

} // namespace

extern "C" void kernel_launch(void* const* d_in, const int* in_sizes, int n_in,
                              void* d_out, int out_size, void* d_ws, size_t ws_size,
                              hipStream_t stream)
{
    const float* Q = (const float*)d_in[0];
    const float* K = (const float*)d_in[1];
    const float* V = (const float*)d_in[2];
    float* O = (float*)d_out;
    dim3 grid(256);        // 8 strip-pairs x 32 bh, 1 block/CU, 36 tiles each
    dim3 block(512);
    hipLaunchKernelGGL(attn_fwd, grid, block, 0, stream, Q, K, V, O);
}

// Round 5
// 130.262 us; speedup vs baseline: 3.6218x; 2.2694x over previous
//
#include <hip/hip_runtime.h>
#include <hip/hip_bf16.h>

namespace {

constexpr int S_LEN = 2048;
constexpr int DH    = 128;
constexpr int KVB   = 64;             // kv rows per tile
constexpr int QT    = 128;            // q rows per block (4 waves x 32)
constexpr int NQT   = S_LEN / QT;     // 16 strips
constexpr int NKT   = S_LEN / KVB;    // 32 kv tiles
constexpr int TILE_SH = KVB * DH;     // 8192 shorts = 16 KB per tile image

typedef __attribute__((ext_vector_type(4)))  float  f32x4;
typedef __attribute__((ext_vector_type(16))) float  f32x16;
typedef __attribute__((ext_vector_type(8)))  short  short8;
typedef __attribute__((ext_vector_type(8)))  __bf16 bf16x8;

typedef __attribute__((address_space(1))) const unsigned int gu32;
typedef __attribute__((address_space(3))) unsigned int       lu32;

__device__ __forceinline__ short f2bf(float x) {
    return __builtin_bit_cast(short, __float2bfloat16(x));
}
__device__ __forceinline__ unsigned pk2(float a, float b) {
    unsigned short lo = __builtin_bit_cast(unsigned short, __float2bfloat16(a));
    unsigned short hh = __builtin_bit_cast(unsigned short, __float2bfloat16(b));
    return (unsigned)lo | ((unsigned)hh << 16);
}
__device__ __forceinline__ f32x16 mfma32(short8 a, short8 b, f32x16 c) {
    return __builtin_amdgcn_mfma_f32_32x32x16_bf16(
        __builtin_bit_cast(bf16x8, a), __builtin_bit_cast(bf16x8, b), c, 0, 0, 0);
}
__device__ __forceinline__ f32x16 zero16() {
    f32x16 z;
    #pragma unroll
    for (int i = 0; i < 16; ++i) z[i] = 0.f;
    return z;
}
__device__ __forceinline__ short8 mk8(unsigned a, unsigned b, unsigned c, unsigned d) {
    uint4 u; u.x = a; u.y = b; u.z = c; u.w = d;
    return __builtin_bit_cast(short8, u);
}

// ---------------- pre-pass: fp32 K,V -> bf16 swizzled LDS tile images in ws --------
// K image:  e = (row*DH + col) ^ ((row&7)<<3), holds K[row][col] (bf16)
// V image:  e = (d*KVB + k)  ^ ((d&7)<<3),    holds V[k][d]     (bf16, transposed)
__global__ void __launch_bounds__(256)
prep_kv(const float* __restrict__ Kp, const float* __restrict__ Vp,
        short* __restrict__ wsK, short* __restrict__ wsV)
{
    const int blk = blockIdx.x;          // 0..1023 = bh*32 + kt
    const int bh  = blk >> 5;
    const int kt  = blk & 31;
    const int tid = threadIdx.x;

    const float* Ks = Kp + (size_t)bh * (S_LEN * DH) + (size_t)kt * KVB * DH;
    const float* Vs = Vp + (size_t)bh * (S_LEN * DH) + (size_t)kt * KVB * DH;
    short* dK = wsK + (size_t)blk * TILE_SH;
    short* dV = wsV + (size_t)blk * TILE_SH;

    #pragma unroll
    for (int i = 0; i < 4; ++i) {
        const int e = (tid + 256 * i) * 8;      // dest short index (8 per thread)
        // ---- K ----
        {
            const int row  = e >> 7;
            const int scol = (e & 127) ^ ((row & 7) << 3);
            f32x4 a = *reinterpret_cast<const f32x4*>(Ks + row * DH + scol);
            f32x4 b = *reinterpret_cast<const f32x4*>(Ks + row * DH + scol + 4);
            uint4 u;
            u.x = pk2(a[0], a[1]); u.y = pk2(a[2], a[3]);
            u.z = pk2(b[0], b[1]); u.w = pk2(b[2], b[3]);
            *reinterpret_cast<uint4*>(&dK[e]) = u;
        }
        // ---- V^T ----
        {
            const int d  = e >> 6;
            const int kb = (e & 63) ^ ((d & 7) << 3);
            float t[8];
            #pragma unroll
            for (int m2 = 0; m2 < 8; ++m2)
                t[m2] = Vs[(size_t)(kb + m2) * DH + d];
            uint4 u;
            u.x = pk2(t[0], t[1]); u.y = pk2(t[2], t[3]);
            u.z = pk2(t[4], t[5]); u.w = pk2(t[6], t[7]);
            *reinterpret_cast<uint4*>(&dV[e]) = u;
        }
    }
}

// ---------------- main attention kernel ----------------
__global__ void __launch_bounds__(256, 2)
attn_fwd(const float* __restrict__ Qp, const short* __restrict__ wsK,
         const short* __restrict__ wsV, float* __restrict__ Op)
{
    __shared__ __align__(16) short ksm[2][TILE_SH];   // K  [64][128] swizzled
    __shared__ __align__(16) short vtm[2][TILE_SH];   // V^T[128][64] swizzled

    const int x   = blockIdx.x;                       // 0..15 strip selector
    const int qt  = (x < 8) ? (NQT - 1 - x) : (x - 8);  // XCD-balanced heavy/light
    const int bh  = blockIdx.y;
    const int tid = threadIdx.x;
    const int w   = tid >> 6;
    const int l   = tid & 63;
    const int r31 = l & 31;
    const int hi  = l >> 5;

    const size_t base = (size_t)bh * (S_LEN * DH);
    const short* Kt = wsK + (size_t)bh * NKT * TILE_SH;
    const short* Vt = wsV + (size_t)bh * NKT * TILE_SH;

    const int qw = qt * QT + 32 * w;       // wave's first q row
    const int qg = qw + r31;               // lane's q row
    const int nkt = (qt + 1) * (QT / KVB);

    const float QS = 0.08838834764831845f * 1.4426950408889634f; // 1/sqrt(128)*log2(e)

    // ---- async staging: each wave loads its 4KB quarter of K and V images ----
    auto stage = [&](int kt, int b) {
        const short* gk = Kt + (size_t)kt * TILE_SH + w * 2048 + l * 8;
        const short* gv = Vt + (size_t)kt * TILE_SH + w * 2048 + l * 8;
        short* lk = &ksm[b][w * 2048];
        short* lv = &vtm[b][w * 2048];
        #pragma unroll
        for (int j = 0; j < 4; ++j) {
            __builtin_amdgcn_global_load_lds((gu32*)(gk + j * 512), (lu32*)(lk + j * 512), 16, 0, 0);
            __builtin_amdgcn_global_load_lds((gu32*)(gv + j * 512), (lu32*)(lv + j * 512), 16, 0, 0);
        }
    };
    auto ldK = [&](const short* ks, int row, int col) -> short8 {
        return *reinterpret_cast<const short8*>(&ks[(row * DH + col) ^ ((row & 7) << 3)]);
    };
    auto ldV = [&](const short* vt, int vr, int col) -> short8 {
        return *reinterpret_cast<const short8*>(&vt[(vr * KVB + col) ^ ((vr & 7) << 3)]);
    };

    // ---- Q fragments (B-operand: col=q=r31, k-elem=8hi+j per 16-d slice) ----
    short8 qb[8];
    {
        const float* qrow = Qp + base + (size_t)qg * DH + 8 * hi;
        #pragma unroll
        for (int t = 0; t < 8; ++t) {
            f32x4 f0 = *reinterpret_cast<const f32x4*>(qrow + 16 * t);
            f32x4 f1 = *reinterpret_cast<const f32x4*>(qrow + 16 * t + 4);
            qb[t] = mk8(pk2(f0[0] * QS, f0[1] * QS), pk2(f0[2] * QS, f0[3] * QS),
                        pk2(f1[0] * QS, f1[1] * QS), pk2(f1[2] * QS, f1[3] * QS));
        }
    }

    f32x16 acc_o[4];
    #pragma unroll
    for (int i = 0; i < 4; ++i) acc_o[i] = zero16();
    float m_run = -1e30f, l_run = 0.f;

    // ---- prologue ----
    stage(0, 0);
    asm volatile("s_waitcnt vmcnt(0)" ::: "memory");
    __syncthreads();
    int cur = 0;

    for (int kt = 0; kt < nkt; ++kt) {
        const int k0 = kt * KVB;
        const bool more = (kt + 1 < nkt);
        if (more) stage(kt + 1, cur ^ 1);    // overlap HBM latency with compute

        if (k0 <= qw) {
            const bool useS1 = (k0 < qw);
            const short* ks = ksm[cur];
            const short* vt = vtm[cur];

            // ---- QK^T (swapped): lane q=r31, k=crow(rg,hi) (+32 in s1) ----
            f32x16 s0 = zero16(), s1 = zero16();
            __builtin_amdgcn_s_setprio(1);
            #pragma unroll
            for (int t = 0; t < 8; ++t)
                s0 = mfma32(ldK(ks, r31, 16 * t + 8 * hi), qb[t], s0);
            if (useS1) {
                #pragma unroll
                for (int t = 0; t < 8; ++t)
                    s1 = mfma32(ldK(ks, r31 + 32, 16 * t + 8 * hi), qb[t], s1);
            }
            __builtin_amdgcn_s_setprio(0);

            // ---- causal mask (diagonal tiles only) ----
            if (k0 == qw) {
                #pragma unroll
                for (int rg = 0; rg < 16; ++rg) {
                    const int kl = (rg & 3) + 8 * (rg >> 2) + 4 * hi;
                    if (k0 + kl > qg) s0[rg] = -3.0e38f;
                }
            }
            if (useS1 && (k0 + 32 == qw)) {
                #pragma unroll
                for (int rg = 0; rg < 16; ++rg) {
                    const int kl = (rg & 3) + 8 * (rg >> 2) + 4 * hi;
                    if (k0 + 32 + kl > qg) s1[rg] = -3.0e38f;
                }
            }

            // ---- online softmax (in-register, exp2 domain, defer-max T13) ----
            float tm[16];
            #pragma unroll
            for (int i = 0; i < 16; ++i) tm[i] = useS1 ? fmaxf(s0[i], s1[i]) : s0[i];
            #pragma unroll
            for (int st = 8; st > 0; st >>= 1)
                #pragma unroll
                for (int i = 0; i < st; ++i) tm[i] = fmaxf(tm[i], tm[i + st]);
            const float mt = fmaxf(tm[0], __shfl_xor(tm[0], 32));

            float mn = m_run;
            if (!__all(mt <= m_run + 8.0f)) {
                mn = fmaxf(m_run, mt);
                const float al = exp2f(m_run - mn);
                m_run = mn;
                l_run *= al;
                #pragma unroll
                for (int d0 = 0; d0 < 4; ++d0)
                    #pragma unroll
                    for (int i = 0; i < 16; ++i) acc_o[d0][i] *= al;
            }

            #pragma unroll
            for (int i = 0; i < 16; ++i) s0[i] = exp2f(s0[i] - mn);
            if (useS1) {
                #pragma unroll
                for (int i = 0; i < 16; ++i) s1[i] = exp2f(s1[i] - mn);
            }
            float ts[16];
            #pragma unroll
            for (int i = 0; i < 16; ++i) ts[i] = useS1 ? (s0[i] + s1[i]) : s0[i];
            #pragma unroll
            for (int st = 8; st > 0; st >>= 1)
                #pragma unroll
                for (int i = 0; i < st; ++i) ts[i] += ts[i + st];
            l_run += ts[0] + __shfl_xor(ts[0], 32);

            // ---- P -> bf16 B-fragments (cvt_pk + permlane32_swap T12) ----
            short8 pbs[4];
            auto mkpb = [&](const f32x16& s, short8* out) {
                #pragma unroll
                for (int h = 0; h < 2; ++h) {
                    unsigned a1 = pk2(s[8 * h + 0], s[8 * h + 1]);
                    unsigned a2 = pk2(s[8 * h + 2], s[8 * h + 3]);
                    unsigned b1 = pk2(s[8 * h + 4], s[8 * h + 5]);
                    unsigned b2 = pk2(s[8 * h + 6], s[8 * h + 7]);
                    asm volatile("v_permlane32_swap_b32 %0, %1" : "+v"(a1), "+v"(b1));
                    asm volatile("v_permlane32_swap_b32 %0, %1" : "+v"(a2), "+v"(b2));
                    uint4 u; u.x = a1; u.y = a2; u.z = b1; u.w = b2;
                    out[h] = __builtin_bit_cast(short8, u);
                }
            };
            mkpb(s0, &pbs[0]);
            if (useS1) mkpb(s1, &pbs[2]);

            // ---- PV: O^T = V^T x P^T ----
            __builtin_amdgcn_s_setprio(1);
            #pragma unroll
            for (int d0 = 0; d0 < 4; ++d0) {
                const int vr = 32 * d0 + r31;
                acc_o[d0] = mfma32(ldV(vt, vr, 8 * hi), pbs[0], acc_o[d0]);
                acc_o[d0] = mfma32(ldV(vt, vr, 16 + 8 * hi), pbs[1], acc_o[d0]);
            }
            if (useS1) {
                #pragma unroll
                for (int d0 = 0; d0 < 4; ++d0) {
                    const int vr = 32 * d0 + r31;
                    acc_o[d0] = mfma32(ldV(vt, vr, 32 + 8 * hi), pbs[2], acc_o[d0]);
                    acc_o[d0] = mfma32(ldV(vt, vr, 48 + 8 * hi), pbs[3], acc_o[d0]);
                }
            }
            __builtin_amdgcn_s_setprio(0);
        }

        if (more) {
            asm volatile("s_waitcnt vmcnt(0)" ::: "memory");
            __syncthreads();                 // one barrier per tile
            cur ^= 1;
        }
    }

    // ---- epilogue: normalize, store fp32 ----
    const float rl = 1.0f / l_run;
    float* orow = Op + base + (size_t)qg * DH;
    #pragma unroll
    for (int d0 = 0; d0 < 4; ++d0) {
        #pragma unroll
        for (int rg = 0; rg < 4; ++rg) {
            f32x4 v;
            v[0] = acc_o[d0][4 * rg + 0] * rl;
            v[1] = acc_o[d0][4 * rg + 1] * rl;
            v[2] = acc_o[d0][4 * rg + 2] * rl;
            v[3] = acc_o[d0][4 * rg + 3] * rl;
            *reinterpret_cast<f32x4*>(orow + 32 * d0 + 8 * rg + 4 * hi) = v;
        }
    }
}

} // namespace

extern "C" void kernel_launch(void* const* d_in, const int* in_sizes, int n_in,
                              void* d_out, int out_size, void* d_ws, size_t ws_size,
                              hipStream_t stream)
{
    const float* Q = (const float*)d_in[0];
    const float* K = (const float*)d_in[1];
    const float* V = (const float*)d_in[2];
    float* O = (float*)d_out;

    short* wsK = (short*)d_ws;                          // 32*32 tiles * 16 KB = 16.78 MB
    short* wsV = wsK + (size_t)32 * NKT * TILE_SH;      // +16.78 MB (ws >= 33.6 MB)

    hipLaunchKernelGGL(prep_kv, dim3(32 * NKT), dim3(256), 0, stream, K, V, wsK, wsV);
    hipLaunchKernelGGL(attn_fwd, dim3(NQT, 32), dim3(256), 0, stream, Q, wsK, wsV, O);
}